// Round 2
// baseline (82.533 us; speedup 1.0000x reference)
//
#include <hip/hip_runtime.h>
#include <math.h>

#define B 64
#define P 1024
#define L 16
#define H 256
#define K 64

__device__ __forceinline__ float wsum(float v){
  #pragma unroll
  for (int o = 32; o >= 1; o >>= 1) v += __shfl_xor(v, o, 64);
  return v;
}
__device__ __forceinline__ float wmaxr(float v){
  #pragma unroll
  for (int o = 32; o >= 1; o >>= 1) v = fmaxf(v, __shfl_xor(v, o, 64));
  return v;
}
__device__ __forceinline__ void wargmax(float &v, int &i){
  #pragma unroll
  for (int o = 32; o >= 1; o >>= 1){
    float v2 = __shfl_xor(v, o, 64);
    int   i2 = __shfl_xor(i, o, 64);
    if (v2 > v || (v2 == v && i2 < i)){ v = v2; i = i2; }
  }
}
__device__ __forceinline__ unsigned fkey(float f){
  unsigned b = __float_as_uint(f);
  return (b & 0x80000000u) ? ~b : (b | 0x80000000u);
}
__device__ __forceinline__ float dot4(float4 a, float4 b){
  return a.x*b.x + a.y*b.y + a.z*b.z + a.w*b.w;
}
// bank-group swizzle for row-major float4 tiles: keeps 64-lane b128 reads
// spread across all 8 bank-groups for row=lane AND row=f(tid&15) patterns.
__device__ __forceinline__ int gsw(int r){ return (r ^ (r >> 3)) & 7; }

// ---------------- kernel 1: radix-select top-64 per batch + IoU + w ----------------
__global__ __launch_bounds__(256) void k_topk_iou(
    const float* __restrict__ pred_center, const float* __restrict__ pred_size,
    const float* __restrict__ obj, const float* __restrict__ ref_center,
    const int* __restrict__ ref_cls, const float* __restrict__ ref_res,
    const float* __restrict__ mean_sz, const int* __restrict__ epoch_p,
    int* __restrict__ inds, float* __restrict__ iou_ws, float* __restrict__ w_ws)
{
  __shared__ int hist[256];
  __shared__ int s_digit, s_cum;
  __shared__ int waveTot[4];
  __shared__ int sel[K];
  __shared__ float ctrS[K][3], szS[K][3];
  int b = blockIdx.x, tid = threadIdx.x, lane = tid & 63, wave = tid >> 6;

  const float4* o4 = (const float4*)(obj + (size_t)b*P*2);
  float4 va = o4[tid*2], vb = o4[tid*2+1];
  unsigned kj[4] = { fkey(va.y - va.x), fkey(va.w - va.z),
                     fkey(vb.y - vb.x), fkey(vb.w - vb.z) };

  unsigned prefix = 0; int rem = K;
  for (int pass = 0; pass < 4; ++pass){
    int shift = 24 - pass*8;
    hist[tid] = 0;
    __syncthreads();
    #pragma unroll
    for (int j = 0; j < 4; ++j){
      unsigned kk = kj[j];
      bool cand = (pass == 0) || ((kk >> (shift + 8)) == prefix);
      if (cand) atomicAdd(&hist[(kk >> shift) & 0xff], 1);
    }
    __syncthreads();
    int d = 255 - tid;
    int h = hist[d];
    int s = h;
    #pragma unroll
    for (int o = 1; o < 64; o <<= 1){ int t = __shfl_up(s, o, 64); if (lane >= o) s += t; }
    if (lane == 63) waveTot[wave] = s;
    __syncthreads();
    #pragma unroll
    for (int q = 0; q < 3; ++q) if (q < wave) s += waveTot[q];
    if (s >= rem && s - h < rem){ s_digit = d; s_cum = s - h; }
    __syncthreads();
    prefix = (prefix << 8) | (unsigned)s_digit;
    rem -= s_cum;
    __syncthreads();
  }
  unsigned T = prefix;
  int remFinal = rem;

  int eqc = 0;
  #pragma unroll
  for (int j = 0; j < 4; ++j) eqc += (kj[j] == T) ? 1 : 0;
  int v = eqc;
  #pragma unroll
  for (int o = 1; o < 64; o <<= 1){ int t = __shfl_up(v, o, 64); if (lane >= o) v += t; }
  if (lane == 63) waveTot[wave] = v;
  __syncthreads();
  int off = 0;
  for (int q = 0; q < wave; ++q) off += waveTot[q];
  int e = off + v - eqc;
  __syncthreads();

  int selc = 0; bool ch[4];
  #pragma unroll
  for (int j = 0; j < 4; ++j){
    bool g = kj[j] > T;
    bool q = (kj[j] == T) && (e < remFinal);
    if (kj[j] == T) e++;
    ch[j] = g || q; selc += ch[j] ? 1 : 0;
  }
  v = selc;
  #pragma unroll
  for (int o = 1; o < 64; o <<= 1){ int t = __shfl_up(v, o, 64); if (lane >= o) v += t; }
  if (lane == 63) waveTot[wave] = v;
  __syncthreads();
  off = 0;
  for (int q = 0; q < wave; ++q) off += waveTot[q];
  int slot = off + v - selc;
  #pragma unroll
  for (int j = 0; j < 4; ++j) if (ch[j]) sel[slot++] = tid*4 + j;
  __syncthreads();

  if (tid < K){
    int idx = sel[tid];
    inds[b*K + tid] = idx;
    #pragma unroll
    for (int dd = 0; dd < 3; ++dd){
      ctrS[tid][dd] = pred_center[((size_t)b*P + idx)*3 + dd];
      szS [tid][dd] = pred_size [((size_t)b*P + idx)*3 + dd];
    }
  }
  __syncthreads();

  int ep = epoch_p[0];
  float pr = ep <= 0 ? 0.f : (ep >= 80 ? 1.f : ep / 80.f);
  float thr = 0.05f + 0.3f * pr;
  float gamma = 1.f + 2.f * pr;

  for (int l = wave; l < L; l += 4){
    int cls = ref_cls[b*L + l];
    float gs[3], gc[3]; float volg = 1.f;
    #pragma unroll
    for (int dd = 0; dd < 3; ++dd){
      gs[dd] = mean_sz[cls*3+dd] + ref_res[((size_t)b*L+l)*3+dd] + 0.01f;
      gc[dd] = ref_center[((size_t)b*L+l)*3+dd];
      volg *= gs[dd];
    }
    int k = lane;
    float inter = 1.f, volp = 1.f;
    #pragma unroll
    for (int dd = 0; dd < 3; ++dd){
      float pc = ctrS[k][dd], ps = szS[k][dd];
      float lo = fmaxf(gc[dd]-gs[dd]*0.5f, pc-ps*0.5f);
      float hi = fminf(gc[dd]+gs[dd]*0.5f, pc+ps*0.5f);
      inter *= fmaxf(hi-lo, 0.f);
      volp *= ps;
    }
    float iou = inter / (volg + volp - inter + 1e-7f);
    float wv = (iou >= thr) ? powf(iou, gamma) : 0.f;
    float S = wsum(wv);
    float av = iou; int ai = k;
    wargmax(av, ai);
    float wfin = (S < 1e-6f) ? ((k == ai) ? 1.f : 0.f) : wv;
    iou_ws[((size_t)b*L + l)*K + k] = iou;
    w_ws  [((size_t)b*L + l)*K + k] = wfin;
  }
}

// ---------------- kernel 2: fused 3x GEMM  C = A @ W^T (gather fused) ----------------
// Row-major swizzled float4 tiles, b128-only LDS traffic, 32-h chunks.
__global__ __launch_bounds__(256) void k_gemm(
    const float* __restrict__ bbox_feature, const int* __restrict__ inds,
    const float* __restrict__ lang_emb,
    const float* __restrict__ Wpc, const float* __restrict__ Wpci,
    const float* __restrict__ Wtext,
    float* __restrict__ boxr, float* __restrict__ boxri, float* __restrict__ texr)
{
  __shared__ __align__(16) float4 At[512], Wt[512];   // [64 rows][8 slots] each
  int gb = blockIdx.x;
  const float *W; float *C; int m0; bool gat;
  if (gb < 64)       { W = Wpc;   C = boxr;  m0 = gb*64;       gat = true;  }
  else if (gb < 128) { W = Wpci;  C = boxri; m0 = (gb-64)*64;  gat = true;  }
  else               { W = Wtext; C = texr;  m0 = (gb-128)*64; gat = false; }
  int bcol = blockIdx.y * 64;
  int tid = threadIdx.x;
  int tr = tid >> 4, tc = tid & 15;
  int ra = tid >> 3, cs = tid & 7;          // staging: rows ra and ra+32, slot cs
  int r0 = m0 + ra, r1 = m0 + ra + 32;
  const float4* A0 = (const float4*)(gat ? bbox_feature + ((size_t)(r0 >> 6)*P + inds[r0])*H
                                         : lang_emb + (size_t)r0*H);
  const float4* A1 = (const float4*)(gat ? bbox_feature + ((size_t)(r1 >> 6)*P + inds[r1])*H
                                         : lang_emb + (size_t)r1*H);
  const float4* W0 = (const float4*)(W + (size_t)(bcol + ra)*H);
  const float4* W1 = (const float4*)(W + (size_t)(bcol + ra + 32)*H);
  int sw0 = cs ^ gsw(ra), sw1 = cs ^ gsw(ra + 32);
  float acc[4][4] = {};
  for (int h0 = 0; h0 < 64; h0 += 8){       // h0 in float4 units
    At[ra*8        + sw0] = A0[h0 + cs];
    At[(ra+32)*8   + sw1] = A1[h0 + cs];
    Wt[ra*8        + sw0] = W0[h0 + cs];
    Wt[(ra+32)*8   + sw1] = W1[h0 + cs];
    __syncthreads();
    #pragma unroll
    for (int c = 0; c < 8; ++c){
      float4 av[4], wv[4];
      #pragma unroll
      for (int i = 0; i < 4; ++i) av[i] = At[(tr*4+i)*8 + (c ^ gsw(tr*4+i))];
      #pragma unroll
      for (int j = 0; j < 4; ++j) wv[j] = Wt[(tc*4+j)*8 + (c ^ gsw(tc*4+j))];
      #pragma unroll
      for (int i = 0; i < 4; ++i)
        #pragma unroll
        for (int j = 0; j < 4; ++j) acc[i][j] += dot4(av[i], wv[j]);
    }
    __syncthreads();
  }
  #pragma unroll
  for (int i = 0; i < 4; ++i){
    float4 v = make_float4(acc[i][0],acc[i][1],acc[i][2],acc[i][3]);
    *(float4*)&C[(size_t)(m0+tr*4+i)*H + bcol + tc*4] = v;
  }
}

// ---------------- kernel 3: contrast losses ----------------
// blocks 0..63: lang loss for batch b (chunked swizzled tiles).
// blocks 64..319: iou loss; idx=blk-64 -> b=idx>>2, rows k0=(idx&3)*16..+15;
//   full 64x256 boxri tile staged once into 64KB dynamic LDS, one barrier.
__global__ __launch_bounds__(256) void k_contrast(
    const float* __restrict__ texr, const float* __restrict__ boxr,
    const float* __restrict__ boxri,
    const float* __restrict__ iou_ws, const float* __restrict__ w_ws,
    const int* __restrict__ lang_num, const float* __restrict__ log_inv_tau,
    const int* __restrict__ epoch_p, float* __restrict__ part)
{
  extern __shared__ __align__(16) float smem[];
  int tid = threadIdx.x, lane = tid & 63, wave = tid >> 6;
  int ep = epoch_p[0];
  float pr = ep <= 0 ? 0.f : (ep >= 80 ? 1.f : ep / 80.f);
  float min_tau = fmaxf(0.08f - 0.04f*pr, 1e-6f);
  float itau = fminf(fminf(expf(log_inv_tau[0]), 100.f), 1.f/min_tau);

  if (blockIdx.x < 64){
    // ---------------- lang branch ----------------
    int b = blockIdx.x;
    float4* BT = (float4*)smem;            // [64][8] swizzled
    float4* TT = (float4*)smem + 512;      // [16][8] swizzled
    float*  red = smem + 2560;
    const float4* bsrc = (const float4*)(boxr + (size_t)b*K*H);
    const float4* tsrc = (const float4*)(texr + (size_t)b*L*H);
    float acc[4] = {0,0,0,0}, nt2[4] = {0,0,0,0};
    float nb2 = 0.f;
    for (int h0 = 0; h0 < 64; h0 += 8){
      #pragma unroll
      for (int j = 0; j < 2; ++j){
        int i4 = tid + 256*j;              // 0..511
        int row = i4 >> 3, c = i4 & 7;
        BT[row*8 + (c ^ gsw(row))] = bsrc[row*64 + h0 + c];
      }
      if (tid < 128){
        int row = tid >> 3, c = tid & 7;
        TT[row*8 + (c ^ gsw(row))] = tsrc[row*64 + h0 + c];
      }
      __syncthreads();
      #pragma unroll
      for (int c = 0; c < 8; ++c){
        float4 bx = BT[lane*8 + (c ^ gsw(lane))];
        nb2 += dot4(bx, bx);
        #pragma unroll
        for (int i = 0; i < 4; ++i){
          int l = wave*4 + i;
          float4 tv = TT[l*8 + (c ^ gsw(l))];
          acc[i] += dot4(tv, bx);
          nt2[i] += dot4(tv, tv);
        }
      }
      __syncthreads();
    }
    float nb = fmaxf(sqrtf(nb2), 1e-12f);
    int ln = lang_num[b];
    float bacc = 0.f;
    #pragma unroll
    for (int i = 0; i < 4; ++i){
      int l = wave*4 + i;
      if (l < ln){
        float sv = acc[i] / (fmaxf(sqrtf(nt2[i]), 1e-12f) * nb);
        float wv  = w_ws [((size_t)b*L + l)*K + lane];
        float iou = iou_ws[((size_t)b*L + l)*K + lane];
        float S2 = wsum(wv);
        float target = wv / (S2 + 1e-6f);
        float tsum = S2 / (S2 + 1e-6f);
        float t2 = target / (tsum + 1e-6f);
        float z = sv * itau;
        float zmax = wmaxr(z);
        float se = wsum(expf(z - zmax));
        float lp = z - zmax - logf(se);
        float ce = -wsum(t2 * lp);
        bool neg = iou < 0.05f;
        float sneg = wmaxr(neg ? sv : -INFINITY);
        int anyneg = __any(neg);
        float spos = wsum(sv * target);
        float rank = anyneg ? fmaxf(0.2f - spos + sneg, 0.f) : 0.f;
        bacc += ce + 0.5f*rank;
      }
    }
    if (lane == 0) red[wave] = bacc;
    __syncthreads();
    if (tid == 0) part[b] = red[0]+red[1]+red[2]+red[3];
  } else {
    // ---------------- iou branch: full tile in LDS ----------------
    int idx = blockIdx.x - 64;
    int b = idx >> 2, k0 = (idx & 3) * 16;
    float4* T = (float4*)smem;             // [64][64] swizzled = 64KB
    const float4* src = (const float4*)(boxri + (size_t)b*K*H);
    #pragma unroll
    for (int j = 0; j < 16; ++j){
      int i4 = tid + 256*j;                // 0..4095
      int row = i4 >> 6, c = i4 & 63;
      T[row*64 + (c ^ gsw(row))] = src[i4];
    }
    __syncthreads();

    int r0 = k0 + wave*4;
    float acc[4] = {0,0,0,0};
    float nm2 = 0.f;
    for (int c = 0; c < 64; ++c){
      float4 bx = T[lane*64 + (c ^ gsw(lane))];
      nm2 += dot4(bx, bx);
      #pragma unroll
      for (int i = 0; i < 4; ++i){
        float4 kq = T[(r0+i)*64 + (c ^ gsw(r0+i))];   // broadcast
        acc[i] += dot4(kq, bx);
      }
    }
    float nm = fmaxf(sqrtf(nm2), 1e-12f);
    float lp[4];
    #pragma unroll
    for (int i = 0; i < 4; ++i){
      float nk = __shfl(nm, r0 + i, 64);
      float sv = acc[i] / (nk * nm);
      float z = sv * itau;
      float zmax = wmaxr(z);
      float se = wsum(expf(z - zmax));
      lp[i] = z - zmax - logf(se);
    }
    int ln = lang_num[b];
    float bacc = 0.f;
    for (int l = 0; l < ln; ++l){
      float wv = w_ws[((size_t)b*L + l)*K + lane];
      float S = wsum(wv);
      float contrib = 0.f;
      #pragma unroll
      for (int i = 0; i < 4; ++i){
        float wk = __shfl(wv, r0 + i, 64);
        float g = wsum(wv * lp[i]);
        float a = wk * S;
        float c = wk / ((a + 1e-6f) * (a/(a + 1e-6f) + 1e-6f));
        contrib += c * g;
      }
      bacc += -contrib * (1.f/64.f);
    }
    if (lane == 0) part[64 + idx*4 + wave] = bacc;   // per-wave partial
  }
}

// ---------------- kernel 4: deterministic final reduce ----------------
__global__ __launch_bounds__(256) void k_final(const float* __restrict__ part,
                                               float* __restrict__ out)
{
  __shared__ float red[5];
  int tid = threadIdx.x, lane = tid & 63, wave = tid >> 6;
  float v = part[64 + tid] + part[64 + 256 + tid]
          + part[64 + 512 + tid] + part[64 + 768 + tid];   // 1024 iou partials
  v = wsum(v);
  if (lane == 0) red[wave] = v;
  float u = (wave == 0) ? part[tid] : 0.f;                 // 64 lang partials
  u = wsum(u);
  if (tid == 0) red[4] = u;
  __syncthreads();
  if (tid == 0){
    out[0] = red[4] * (1.f/64.f);
    out[1] = (red[0]+red[1]+red[2]+red[3]) * (1.f/64.f);
  }
}

extern "C" void kernel_launch(void* const* d_in, const int* in_sizes, int n_in,
                              void* d_out, int out_size, void* d_ws, size_t ws_size,
                              hipStream_t stream)
{
  const float* pred_center = (const float*)d_in[0];
  const float* pred_size   = (const float*)d_in[1];
  const float* bbox_feature= (const float*)d_in[2];
  const float* obj         = (const float*)d_in[3];
  const float* lang_emb    = (const float*)d_in[4];
  const int*   lang_num    = (const int*)d_in[5];
  const float* ref_center  = (const float*)d_in[6];
  const int*   ref_cls     = (const int*)d_in[7];
  const float* ref_res     = (const float*)d_in[8];
  const float* mean_sz     = (const float*)d_in[9];
  const float* Wtext       = (const float*)d_in[10];
  const float* Wpc         = (const float*)d_in[11];
  const float* Wpci        = (const float*)d_in[12];
  const float* lit         = (const float*)d_in[13];
  const int*   epoch       = (const int*)d_in[14];

  float* ws = (float*)d_ws;
  int*   inds   = (int*)ws;                 // B*K ints
  float* iou_ws = ws + 4096;                // B*L*K
  float* w_ws   = iou_ws + B*L*K;           // B*L*K
  float* texr   = w_ws + B*L*K;             // B*L*H
  float* boxr   = texr + (size_t)B*L*H;     // B*K*H
  float* boxri  = boxr + (size_t)B*K*H;     // B*K*H
  float* part   = boxri + (size_t)B*K*H;    // 64 lang + 1024 iou wave-partials

  k_topk_iou<<<B, 256, 0, stream>>>(pred_center, pred_size, obj, ref_center,
                                    ref_cls, ref_res, mean_sz, epoch,
                                    inds, iou_ws, w_ws);
  k_gemm<<<dim3(144, 4), 256, 0, stream>>>(bbox_feature, inds, lang_emb,
                                           Wpc, Wpci, Wtext, boxr, boxri, texr);
  k_contrast<<<320, 256, 65536, stream>>>(texr, boxr, boxri,
                                          iou_ws, w_ws, lang_num, lit, epoch, part);
  k_final<<<1, 256, 0, stream>>>(part, (float*)d_out);
}

// Round 3
// 78.187 us; speedup vs baseline: 1.0556x; 1.0556x over previous
//
#include <hip/hip_runtime.h>
#include <math.h>

#define B 64
#define P 1024
#define L 16
#define H 256
#define K 64

__device__ __forceinline__ float wsum(float v){
  #pragma unroll
  for (int o = 32; o >= 1; o >>= 1) v += __shfl_xor(v, o, 64);
  return v;
}
__device__ __forceinline__ float wmaxr(float v){
  #pragma unroll
  for (int o = 32; o >= 1; o >>= 1) v = fmaxf(v, __shfl_xor(v, o, 64));
  return v;
}
__device__ __forceinline__ void wargmax(float &v, int &i){
  #pragma unroll
  for (int o = 32; o >= 1; o >>= 1){
    float v2 = __shfl_xor(v, o, 64);
    int   i2 = __shfl_xor(i, o, 64);
    if (v2 > v || (v2 == v && i2 < i)){ v = v2; i = i2; }
  }
}
__device__ __forceinline__ unsigned fkey(float f){
  unsigned b = __float_as_uint(f);
  return (b & 0x80000000u) ? ~b : (b | 0x80000000u);
}
__device__ __forceinline__ float dot4(float4 a, float4 b){
  return a.x*b.x + a.y*b.y + a.z*b.z + a.w*b.w;
}
__device__ __forceinline__ int gsw(int r){ return (r ^ (r >> 3)) & 7; }

// ---------------- kernel 1: radix-select top-64 per batch + IoU + w ----------------
__global__ __launch_bounds__(256) void k_topk_iou(
    const float* __restrict__ pred_center, const float* __restrict__ pred_size,
    const float* __restrict__ obj, const float* __restrict__ ref_center,
    const int* __restrict__ ref_cls, const float* __restrict__ ref_res,
    const float* __restrict__ mean_sz, const int* __restrict__ epoch_p,
    int* __restrict__ inds, float* __restrict__ iou_ws, float* __restrict__ w_ws)
{
  __shared__ int hist[256];
  __shared__ int s_digit, s_cum;
  __shared__ int waveTot[4];
  __shared__ int sel[K];
  __shared__ float ctrS[K][3], szS[K][3];
  int b = blockIdx.x, tid = threadIdx.x, lane = tid & 63, wave = tid >> 6;

  const float4* o4 = (const float4*)(obj + (size_t)b*P*2);
  float4 va = o4[tid*2], vb = o4[tid*2+1];
  unsigned kj[4] = { fkey(va.y - va.x), fkey(va.w - va.z),
                     fkey(vb.y - vb.x), fkey(vb.w - vb.z) };

  unsigned prefix = 0; int rem = K;
  for (int pass = 0; pass < 4; ++pass){
    int shift = 24 - pass*8;
    hist[tid] = 0;
    __syncthreads();
    #pragma unroll
    for (int j = 0; j < 4; ++j){
      unsigned kk = kj[j];
      bool cand = (pass == 0) || ((kk >> (shift + 8)) == prefix);
      if (cand) atomicAdd(&hist[(kk >> shift) & 0xff], 1);
    }
    __syncthreads();
    int d = 255 - tid;
    int h = hist[d];
    int s = h;
    #pragma unroll
    for (int o = 1; o < 64; o <<= 1){ int t = __shfl_up(s, o, 64); if (lane >= o) s += t; }
    if (lane == 63) waveTot[wave] = s;
    __syncthreads();
    #pragma unroll
    for (int q = 0; q < 3; ++q) if (q < wave) s += waveTot[q];
    if (s >= rem && s - h < rem){ s_digit = d; s_cum = s - h; }
    __syncthreads();
    prefix = (prefix << 8) | (unsigned)s_digit;
    rem -= s_cum;
    __syncthreads();
  }
  unsigned T = prefix;
  int remFinal = rem;

  int eqc = 0;
  #pragma unroll
  for (int j = 0; j < 4; ++j) eqc += (kj[j] == T) ? 1 : 0;
  int v = eqc;
  #pragma unroll
  for (int o = 1; o < 64; o <<= 1){ int t = __shfl_up(v, o, 64); if (lane >= o) v += t; }
  if (lane == 63) waveTot[wave] = v;
  __syncthreads();
  int off = 0;
  for (int q = 0; q < wave; ++q) off += waveTot[q];
  int e = off + v - eqc;
  __syncthreads();

  int selc = 0; bool ch[4];
  #pragma unroll
  for (int j = 0; j < 4; ++j){
    bool g = kj[j] > T;
    bool q = (kj[j] == T) && (e < remFinal);
    if (kj[j] == T) e++;
    ch[j] = g || q; selc += ch[j] ? 1 : 0;
  }
  v = selc;
  #pragma unroll
  for (int o = 1; o < 64; o <<= 1){ int t = __shfl_up(v, o, 64); if (lane >= o) v += t; }
  if (lane == 63) waveTot[wave] = v;
  __syncthreads();
  off = 0;
  for (int q = 0; q < wave; ++q) off += waveTot[q];
  int slot = off + v - selc;
  #pragma unroll
  for (int j = 0; j < 4; ++j) if (ch[j]) sel[slot++] = tid*4 + j;
  __syncthreads();

  if (tid < K){
    int idx = sel[tid];
    inds[b*K + tid] = idx;
    #pragma unroll
    for (int dd = 0; dd < 3; ++dd){
      ctrS[tid][dd] = pred_center[((size_t)b*P + idx)*3 + dd];
      szS [tid][dd] = pred_size [((size_t)b*P + idx)*3 + dd];
    }
  }
  __syncthreads();

  int ep = epoch_p[0];
  float pr = ep <= 0 ? 0.f : (ep >= 80 ? 1.f : ep / 80.f);
  float thr = 0.05f + 0.3f * pr;
  float gamma = 1.f + 2.f * pr;

  for (int l = wave; l < L; l += 4){
    int cls = ref_cls[b*L + l];
    float gs[3], gc[3]; float volg = 1.f;
    #pragma unroll
    for (int dd = 0; dd < 3; ++dd){
      gs[dd] = mean_sz[cls*3+dd] + ref_res[((size_t)b*L+l)*3+dd] + 0.01f;
      gc[dd] = ref_center[((size_t)b*L+l)*3+dd];
      volg *= gs[dd];
    }
    int k = lane;
    float inter = 1.f, volp = 1.f;
    #pragma unroll
    for (int dd = 0; dd < 3; ++dd){
      float pc = ctrS[k][dd], ps = szS[k][dd];
      float lo = fmaxf(gc[dd]-gs[dd]*0.5f, pc-ps*0.5f);
      float hi = fminf(gc[dd]+gs[dd]*0.5f, pc+ps*0.5f);
      inter *= fmaxf(hi-lo, 0.f);
      volp *= ps;
    }
    float iou = inter / (volg + volp - inter + 1e-7f);
    float wv = (iou >= thr) ? powf(iou, gamma) : 0.f;
    float S = wsum(wv);
    float av = iou; int ai = k;
    wargmax(av, ai);
    float wfin = (S < 1e-6f) ? ((k == ai) ? 1.f : 0.f) : wv;
    iou_ws[((size_t)b*L + l)*K + k] = iou;
    w_ws  [((size_t)b*L + l)*K + k] = wfin;
  }
}

// ---------------- kernel 2: fused 3x GEMM  C = A @ W^T (gather fused) ----------------
// Reverted to round-1 version: [16][68] transposed tiles, immediate-offset b128 reads.
__global__ __launch_bounds__(256) void k_gemm(
    const float* __restrict__ bbox_feature, const int* __restrict__ inds,
    const float* __restrict__ lang_emb,
    const float* __restrict__ Wpc, const float* __restrict__ Wpci,
    const float* __restrict__ Wtext,
    float* __restrict__ boxr, float* __restrict__ boxri, float* __restrict__ texr)
{
  __shared__ float As[16][68], Ws[16][68];
  int gb = blockIdx.x;
  const float *W; float *C; int m0; bool gat;
  if (gb < 64)       { W = Wpc;   C = boxr;  m0 = gb*64;       gat = true;  }
  else if (gb < 128) { W = Wpci;  C = boxri; m0 = (gb-64)*64;  gat = true;  }
  else               { W = Wtext; C = texr;  m0 = (gb-128)*64; gat = false; }
  int bcol = blockIdx.y * 64;
  int tid = threadIdx.x;
  int lr = tid >> 2, lc = (tid & 3) * 4;
  int tr = tid >> 4, tc = tid & 15;
  int r = m0 + lr;
  const float* Arow = gat ? bbox_feature + ((size_t)(r >> 6)*P + inds[r])*H
                          : lang_emb + (size_t)r*H;
  const float* Wrow = W + (size_t)(bcol + lr)*H;
  float acc[4][4] = {};
  for (int h0 = 0; h0 < H; h0 += 16){
    float4 av = *(const float4*)&Arow[h0 + lc];
    float4 wv = *(const float4*)&Wrow[h0 + lc];
    As[lc+0][lr]=av.x; As[lc+1][lr]=av.y; As[lc+2][lr]=av.z; As[lc+3][lr]=av.w;
    Ws[lc+0][lr]=wv.x; Ws[lc+1][lr]=wv.y; Ws[lc+2][lr]=wv.z; Ws[lc+3][lr]=wv.w;
    __syncthreads();
    #pragma unroll
    for (int h = 0; h < 16; ++h){
      float4 a = *(const float4*)&As[h][tr*4];
      float4 w = *(const float4*)&Ws[h][tc*4];
      float aa[4] = {a.x,a.y,a.z,a.w};
      float ww[4] = {w.x,w.y,w.z,w.w};
      #pragma unroll
      for (int i = 0; i < 4; ++i)
        #pragma unroll
        for (int j = 0; j < 4; ++j) acc[i][j] += aa[i]*ww[j];
    }
    __syncthreads();
  }
  #pragma unroll
  for (int i = 0; i < 4; ++i){
    float4 v = make_float4(acc[i][0],acc[i][1],acc[i][2],acc[i][3]);
    *(float4*)&C[(size_t)(m0+tr*4+i)*H + bcol + tc*4] = v;
  }
}

// ---------------- kernel 3: fused contrast losses, 256 balanced blocks ----------------
// block = (b = blk>>2, strip s = blk&3). Stages boxri[b] + boxr[b] + texr[b]
// (144KB dynamic LDS, 1 block/CU). iou: simi rows 16s..16s+15 (wave w: 4 rows).
// lang: wave w handles l = 4s + w. All softmax/losses in registers, one barrier.
__global__ __launch_bounds__(256) void k_contrast(
    const float* __restrict__ texr, const float* __restrict__ boxr,
    const float* __restrict__ boxri,
    const float* __restrict__ iou_ws, const float* __restrict__ w_ws,
    const int* __restrict__ lang_num, const float* __restrict__ log_inv_tau,
    const int* __restrict__ epoch_p, float* __restrict__ part)
{
  extern __shared__ __align__(16) float smem[];
  float4* TI = (float4*)smem;                 // [64][64] boxri swizzled
  float4* TB = (float4*)smem + 4096;          // [64][64] boxr swizzled
  float4* TT = (float4*)smem + 8192;          // [16][64] texr swizzled
  int tid = threadIdx.x, lane = tid & 63, wave = tid >> 6;
  int blk = blockIdx.x;
  int b = blk >> 2, s = blk & 3;
  int ep = epoch_p[0];
  float pr = ep <= 0 ? 0.f : (ep >= 80 ? 1.f : ep / 80.f);
  float min_tau = fmaxf(0.08f - 0.04f*pr, 1e-6f);
  float itau = fminf(fminf(expf(log_inv_tau[0]), 100.f), 1.f/min_tau);

  // -------- stage all three tiles --------
  const float4* srcI = (const float4*)(boxri + (size_t)b*K*H);
  const float4* srcB = (const float4*)(boxr  + (size_t)b*K*H);
  const float4* srcT = (const float4*)(texr  + (size_t)b*L*H);
  #pragma unroll
  for (int j = 0; j < 16; ++j){
    int i4 = tid + 256*j;                  // 0..4095
    int row = i4 >> 6, c = i4 & 63;
    int dst = row*64 + (c ^ gsw(row));
    TI[dst] = srcI[i4];
    TB[dst] = srcB[i4];
  }
  #pragma unroll
  for (int j = 0; j < 4; ++j){
    int i4 = tid + 256*j;                  // 0..1023
    int row = i4 >> 6, c = i4 & 63;
    TT[row*64 + (c ^ gsw(row))] = srcT[i4];
  }
  __syncthreads();

  int ln = lang_num[b];

  // -------- iou branch: simi rows r0..r0+3, col m = lane --------
  int r0 = s*16 + wave*4;
  {
    float acc[4] = {0,0,0,0};
    float nm2 = 0.f;
    for (int c = 0; c < 64; ++c){
      float4 bx = TI[lane*64 + (c ^ gsw(lane))];
      nm2 += dot4(bx, bx);
      #pragma unroll
      for (int i = 0; i < 4; ++i){
        float4 kq = TI[(r0+i)*64 + (c ^ gsw(r0+i))];   // broadcast
        acc[i] += dot4(kq, bx);
      }
    }
    float nm = fmaxf(sqrtf(nm2), 1e-12f);
    float lp[4];
    #pragma unroll
    for (int i = 0; i < 4; ++i){
      float nk = __shfl(nm, r0 + i, 64);
      float sv = acc[i] / (nk * nm);
      float z = sv * itau;
      float zmax = wmaxr(z);
      float se = wsum(expf(z - zmax));
      lp[i] = z - zmax - logf(se);
    }
    float bacc = 0.f;
    for (int l = 0; l < ln; ++l){
      float wv = w_ws[((size_t)b*L + l)*K + lane];
      float S = wsum(wv);
      float contrib = 0.f;
      #pragma unroll
      for (int i = 0; i < 4; ++i){
        float wk = __shfl(wv, r0 + i, 64);
        float g = wsum(wv * lp[i]);
        float a = wk * S;
        float c = wk / ((a + 1e-6f) * (a/(a + 1e-6f) + 1e-6f));
        contrib += c * g;
      }
      bacc += -contrib * (1.f/64.f);
    }
    if (lane == 0) part[blk*4 + wave] = bacc;
  }

  // -------- lang branch: row l = 4s + wave, col k = lane --------
  {
    int l = s*4 + wave;
    float acc = 0.f, nb2 = 0.f, nt2 = 0.f;
    for (int c = 0; c < 64; ++c){
      float4 bx = TB[lane*64 + (c ^ gsw(lane))];
      float4 tv = TT[l*64 + (c ^ gsw(l))];            // broadcast
      acc += dot4(tv, bx);
      nb2 += dot4(bx, bx);
      nt2 += dot4(tv, tv);
    }
    float bacc = 0.f;
    if (l < ln){
      float sv = acc / (fmaxf(sqrtf(nt2), 1e-12f) * fmaxf(sqrtf(nb2), 1e-12f));
      float wv  = w_ws [((size_t)b*L + l)*K + lane];
      float iou = iou_ws[((size_t)b*L + l)*K + lane];
      float S2 = wsum(wv);
      float target = wv / (S2 + 1e-6f);
      float tsum = S2 / (S2 + 1e-6f);
      float t2 = target / (tsum + 1e-6f);
      float z = sv * itau;
      float zmax = wmaxr(z);
      float se = wsum(expf(z - zmax));
      float lp = z - zmax - logf(se);
      float ce = -wsum(t2 * lp);
      bool neg = iou < 0.05f;
      float sneg = wmaxr(neg ? sv : -INFINITY);
      int anyneg = __any(neg);
      float spos = wsum(sv * target);
      float rank = anyneg ? fmaxf(0.2f - spos + sneg, 0.f) : 0.f;
      bacc = ce + 0.5f*rank;
    }
    if (lane == 0) part[1024 + blk*4 + wave] = bacc;
  }
}

// ---------------- kernel 4: deterministic final reduce ----------------
__global__ __launch_bounds__(256) void k_final(const float* __restrict__ part,
                                               float* __restrict__ out)
{
  __shared__ float redI[4], redL[4];
  int tid = threadIdx.x, lane = tid & 63, wave = tid >> 6;
  float vi = part[tid] + part[tid+256] + part[tid+512] + part[tid+768];
  float vl = part[1024+tid] + part[1280+tid] + part[1536+tid] + part[1792+tid];
  vi = wsum(vi);
  vl = wsum(vl);
  if (lane == 0){ redI[wave] = vi; redL[wave] = vl; }
  __syncthreads();
  if (tid == 0){
    out[0] = (redL[0]+redL[1]+redL[2]+redL[3]) * (1.f/64.f);
    out[1] = (redI[0]+redI[1]+redI[2]+redI[3]) * (1.f/64.f);
  }
}

extern "C" void kernel_launch(void* const* d_in, const int* in_sizes, int n_in,
                              void* d_out, int out_size, void* d_ws, size_t ws_size,
                              hipStream_t stream)
{
  const float* pred_center = (const float*)d_in[0];
  const float* pred_size   = (const float*)d_in[1];
  const float* bbox_feature= (const float*)d_in[2];
  const float* obj         = (const float*)d_in[3];
  const float* lang_emb    = (const float*)d_in[4];
  const int*   lang_num    = (const int*)d_in[5];
  const float* ref_center  = (const float*)d_in[6];
  const int*   ref_cls     = (const int*)d_in[7];
  const float* ref_res     = (const float*)d_in[8];
  const float* mean_sz     = (const float*)d_in[9];
  const float* Wtext       = (const float*)d_in[10];
  const float* Wpc         = (const float*)d_in[11];
  const float* Wpci        = (const float*)d_in[12];
  const float* lit         = (const float*)d_in[13];
  const int*   epoch       = (const int*)d_in[14];

  float* ws = (float*)d_ws;
  int*   inds   = (int*)ws;                 // B*K ints
  float* iou_ws = ws + 4096;                // B*L*K
  float* w_ws   = iou_ws + B*L*K;           // B*L*K
  float* texr   = w_ws + B*L*K;             // B*L*H
  float* boxr   = texr + (size_t)B*L*H;     // B*K*H
  float* boxri  = boxr + (size_t)B*K*H;     // B*K*H
  float* part   = boxri + (size_t)B*K*H;    // 1024 iou + 1024 lang wave-partials

  k_topk_iou<<<B, 256, 0, stream>>>(pred_center, pred_size, obj, ref_center,
                                    ref_cls, ref_res, mean_sz, epoch,
                                    inds, iou_ws, w_ws);
  k_gemm<<<dim3(144, 4), 256, 0, stream>>>(bbox_feature, inds, lang_emb,
                                           Wpc, Wpci, Wtext, boxr, boxri, texr);
  k_contrast<<<256, 256, 147456, stream>>>(texr, boxr, boxri,
                                           iou_ws, w_ws, lang_num, lit, epoch, part);
  k_final<<<1, 256, 0, stream>>>(part, (float*)d_out);
}

// Round 4
// 61.577 us; speedup vs baseline: 1.3403x; 1.2697x over previous
//
#include <hip/hip_runtime.h>
#include <math.h>

#define B 64
#define P 1024
#define L 16
#define H 256
#define K 64

__device__ __forceinline__ float wsum(float v){
  #pragma unroll
  for (int o = 32; o >= 1; o >>= 1) v += __shfl_xor(v, o, 64);
  return v;
}
__device__ __forceinline__ float wmaxr(float v){
  #pragma unroll
  for (int o = 32; o >= 1; o >>= 1) v = fmaxf(v, __shfl_xor(v, o, 64));
  return v;
}
__device__ __forceinline__ void wargmax(float &v, int &i){
  #pragma unroll
  for (int o = 32; o >= 1; o >>= 1){
    float v2 = __shfl_xor(v, o, 64);
    int   i2 = __shfl_xor(i, o, 64);
    if (v2 > v || (v2 == v && i2 < i)){ v = v2; i = i2; }
  }
}
__device__ __forceinline__ unsigned fkey(float f){
  unsigned b = __float_as_uint(f);
  return (b & 0x80000000u) ? ~b : (b | 0x80000000u);
}
__device__ __forceinline__ float dot4(float4 a, float4 b){
  return a.x*b.x + a.y*b.y + a.z*b.z + a.w*b.w;
}
__device__ __forceinline__ int gsw(int r){ return (r ^ (r >> 3)) & 7; }

// ------ kernel 1: radix-select top-64 + IoU + w + precomputed iou-loss coeffs c ------
__global__ __launch_bounds__(256) void k_topk_iou(
    const float* __restrict__ pred_center, const float* __restrict__ pred_size,
    const float* __restrict__ obj, const float* __restrict__ ref_center,
    const int* __restrict__ ref_cls, const float* __restrict__ ref_res,
    const float* __restrict__ mean_sz, const int* __restrict__ epoch_p,
    const int* __restrict__ lang_num,
    int* __restrict__ inds, float* __restrict__ iou_ws, float* __restrict__ w_ws,
    float* __restrict__ c_ws)
{
  __shared__ int hist[256];
  __shared__ int s_digit, s_cum;
  __shared__ int waveTot[4];
  __shared__ int sel[K];
  __shared__ float ctrS[K][3], szS[K][3];
  int b = blockIdx.x, tid = threadIdx.x, lane = tid & 63, wave = tid >> 6;

  const float4* o4 = (const float4*)(obj + (size_t)b*P*2);
  float4 va = o4[tid*2], vb = o4[tid*2+1];
  unsigned kj[4] = { fkey(va.y - va.x), fkey(va.w - va.z),
                     fkey(vb.y - vb.x), fkey(vb.w - vb.z) };

  unsigned prefix = 0; int rem = K;
  for (int pass = 0; pass < 4; ++pass){
    int shift = 24 - pass*8;
    hist[tid] = 0;
    __syncthreads();
    #pragma unroll
    for (int j = 0; j < 4; ++j){
      unsigned kk = kj[j];
      bool cand = (pass == 0) || ((kk >> (shift + 8)) == prefix);
      if (cand) atomicAdd(&hist[(kk >> shift) & 0xff], 1);
    }
    __syncthreads();
    int d = 255 - tid;
    int h = hist[d];
    int s = h;
    #pragma unroll
    for (int o = 1; o < 64; o <<= 1){ int t = __shfl_up(s, o, 64); if (lane >= o) s += t; }
    if (lane == 63) waveTot[wave] = s;
    __syncthreads();
    #pragma unroll
    for (int q = 0; q < 3; ++q) if (q < wave) s += waveTot[q];
    if (s >= rem && s - h < rem){ s_digit = d; s_cum = s - h; }
    __syncthreads();
    prefix = (prefix << 8) | (unsigned)s_digit;
    rem -= s_cum;
    __syncthreads();
  }
  unsigned T = prefix;
  int remFinal = rem;

  int eqc = 0;
  #pragma unroll
  for (int j = 0; j < 4; ++j) eqc += (kj[j] == T) ? 1 : 0;
  int v = eqc;
  #pragma unroll
  for (int o = 1; o < 64; o <<= 1){ int t = __shfl_up(v, o, 64); if (lane >= o) v += t; }
  if (lane == 63) waveTot[wave] = v;
  __syncthreads();
  int off = 0;
  for (int q = 0; q < wave; ++q) off += waveTot[q];
  int e = off + v - eqc;
  __syncthreads();

  int selc = 0; bool ch[4];
  #pragma unroll
  for (int j = 0; j < 4; ++j){
    bool g = kj[j] > T;
    bool q = (kj[j] == T) && (e < remFinal);
    if (kj[j] == T) e++;
    ch[j] = g || q; selc += ch[j] ? 1 : 0;
  }
  v = selc;
  #pragma unroll
  for (int o = 1; o < 64; o <<= 1){ int t = __shfl_up(v, o, 64); if (lane >= o) v += t; }
  if (lane == 63) waveTot[wave] = v;
  __syncthreads();
  off = 0;
  for (int q = 0; q < wave; ++q) off += waveTot[q];
  int slot = off + v - selc;
  #pragma unroll
  for (int j = 0; j < 4; ++j) if (ch[j]) sel[slot++] = tid*4 + j;
  __syncthreads();

  if (tid < K){
    int idx = sel[tid];
    inds[b*K + tid] = idx;
    #pragma unroll
    for (int dd = 0; dd < 3; ++dd){
      ctrS[tid][dd] = pred_center[((size_t)b*P + idx)*3 + dd];
      szS [tid][dd] = pred_size [((size_t)b*P + idx)*3 + dd];
    }
  }
  __syncthreads();

  int ep = epoch_p[0];
  float pr = ep <= 0 ? 0.f : (ep >= 80 ? 1.f : ep / 80.f);
  float thr = 0.05f + 0.3f * pr;
  float gamma = 1.f + 2.f * pr;
  int ln = lang_num[b];

  for (int l = wave; l < L; l += 4){
    int cls = ref_cls[b*L + l];
    float gs[3], gc[3]; float volg = 1.f;
    #pragma unroll
    for (int dd = 0; dd < 3; ++dd){
      gs[dd] = mean_sz[cls*3+dd] + ref_res[((size_t)b*L+l)*3+dd] + 0.01f;
      gc[dd] = ref_center[((size_t)b*L+l)*3+dd];
      volg *= gs[dd];
    }
    int k = lane;
    float inter = 1.f, volp = 1.f;
    #pragma unroll
    for (int dd = 0; dd < 3; ++dd){
      float pc = ctrS[k][dd], ps = szS[k][dd];
      float lo = fmaxf(gc[dd]-gs[dd]*0.5f, pc-ps*0.5f);
      float hi = fminf(gc[dd]+gs[dd]*0.5f, pc+ps*0.5f);
      inter *= fmaxf(hi-lo, 0.f);
      volp *= ps;
    }
    float iou = inter / (volg + volp - inter + 1e-7f);
    float wv = (iou >= thr) ? powf(iou, gamma) : 0.f;
    float S = wsum(wv);
    float av = iou; int ai = k;
    wargmax(av, ai);
    float wfin = (S < 1e-6f) ? ((k == ai) ? 1.f : 0.f) : wv;
    iou_ws[((size_t)b*L + l)*K + k] = iou;
    w_ws  [((size_t)b*L + l)*K + k] = wfin;
    // iou-loss coefficient c (exactly the formula from the loss loop), with
    // the l<ln mask folded in.  S over the FINAL row (fallback row sums to 1).
    float Sf = (S < 1e-6f) ? 1.f : S;
    float a = wfin * Sf;
    float c = wfin / ((a + 1e-6f) * (a/(a + 1e-6f) + 1e-6f));
    c_ws[((size_t)b*L + l)*K + k] = (l < ln) ? c : 0.f;
  }
}

// ---------------- kernel 2: fused 3x GEMM  C = A @ W^T (gather fused) ----------------
// Round-1 version: [16][68] transposed tiles, immediate-offset b128 reads.
__global__ __launch_bounds__(256) void k_gemm(
    const float* __restrict__ bbox_feature, const int* __restrict__ inds,
    const float* __restrict__ lang_emb,
    const float* __restrict__ Wpc, const float* __restrict__ Wpci,
    const float* __restrict__ Wtext,
    float* __restrict__ boxr, float* __restrict__ boxri, float* __restrict__ texr)
{
  __shared__ float As[16][68], Ws[16][68];
  int gb = blockIdx.x;
  const float *W; float *C; int m0; bool gat;
  if (gb < 64)       { W = Wpc;   C = boxr;  m0 = gb*64;       gat = true;  }
  else if (gb < 128) { W = Wpci;  C = boxri; m0 = (gb-64)*64;  gat = true;  }
  else               { W = Wtext; C = texr;  m0 = (gb-128)*64; gat = false; }
  int bcol = blockIdx.y * 64;
  int tid = threadIdx.x;
  int lr = tid >> 2, lc = (tid & 3) * 4;
  int tr = tid >> 4, tc = tid & 15;
  int r = m0 + lr;
  const float* Arow = gat ? bbox_feature + ((size_t)(r >> 6)*P + inds[r])*H
                          : lang_emb + (size_t)r*H;
  const float* Wrow = W + (size_t)(bcol + lr)*H;
  float acc[4][4] = {};
  for (int h0 = 0; h0 < H; h0 += 16){
    float4 av = *(const float4*)&Arow[h0 + lc];
    float4 wv = *(const float4*)&Wrow[h0 + lc];
    As[lc+0][lr]=av.x; As[lc+1][lr]=av.y; As[lc+2][lr]=av.z; As[lc+3][lr]=av.w;
    Ws[lc+0][lr]=wv.x; Ws[lc+1][lr]=wv.y; Ws[lc+2][lr]=wv.z; Ws[lc+3][lr]=wv.w;
    __syncthreads();
    #pragma unroll
    for (int h = 0; h < 16; ++h){
      float4 a = *(const float4*)&As[h][tr*4];
      float4 w = *(const float4*)&Ws[h][tc*4];
      float aa[4] = {a.x,a.y,a.z,a.w};
      float ww[4] = {w.x,w.y,w.z,w.w};
      #pragma unroll
      for (int i = 0; i < 4; ++i)
        #pragma unroll
        for (int j = 0; j < 4; ++j) acc[i][j] += aa[i]*ww[j];
    }
    __syncthreads();
  }
  #pragma unroll
  for (int i = 0; i < 4; ++i){
    float4 v = make_float4(acc[i][0],acc[i][1],acc[i][2],acc[i][3]);
    *(float4*)&C[(size_t)(m0+tr*4+i)*H + bcol + tc*4] = v;
  }
}

// ---------------- kernel 3: contrast losses, 320 co-resident blocks ----------------
// blocks 0..63   : lang loss, batch b = blk (stages boxr[b] 64KB + texr[b] 16KB)
// blocks 64..319 : iou loss, idx=blk-64, b=idx>>2, rows r0 = (idx&3)*16 + wave*4
//                  (stages boxri[b] 64KB).  81920B dynamic LDS -> 2 blocks/CU.
// iou loss uses the bilinear identity: loss = -(1/64) sum_{k,m} M[k,m]*lp[k,m],
// M[k,m] = sum_l c[l,k]*w[l,m]  -- no serial per-l shuffle chains.
__global__ __launch_bounds__(256) void k_contrast(
    const float* __restrict__ texr, const float* __restrict__ boxr,
    const float* __restrict__ boxri,
    const float* __restrict__ iou_ws, const float* __restrict__ w_ws,
    const float* __restrict__ c_ws,
    const int* __restrict__ lang_num, const float* __restrict__ log_inv_tau,
    const int* __restrict__ epoch_p, float* __restrict__ part)
{
  extern __shared__ __align__(16) float smem[];
  int tid = threadIdx.x, lane = tid & 63, wave = tid >> 6;
  int ep = epoch_p[0];
  float pr = ep <= 0 ? 0.f : (ep >= 80 ? 1.f : ep / 80.f);
  float min_tau = fmaxf(0.08f - 0.04f*pr, 1e-6f);
  float itau = fminf(fminf(expf(log_inv_tau[0]), 100.f), 1.f/min_tau);

  if (blockIdx.x < 64){
    // ---------------- lang branch ----------------
    int b = blockIdx.x;
    float4* TB = (float4*)smem;            // [64][64] boxr swizzled
    float4* TT = (float4*)smem + 4096;     // [16][64] texr swizzled
    const float4* srcB = (const float4*)(boxr + (size_t)b*K*H);
    const float4* srcT = (const float4*)(texr + (size_t)b*L*H);
    #pragma unroll
    for (int j = 0; j < 16; ++j){
      int i4 = tid + 256*j;
      int row = i4 >> 6, c = i4 & 63;
      TB[row*64 + (c ^ gsw(row))] = srcB[i4];
    }
    #pragma unroll
    for (int j = 0; j < 4; ++j){
      int i4 = tid + 256*j;
      int row = i4 >> 6, c = i4 & 63;
      TT[row*64 + (c ^ gsw(row))] = srcT[i4];
    }
    __syncthreads();

    float acc[4] = {0,0,0,0}, nt2[4] = {0,0,0,0};
    float nb2 = 0.f;
    for (int c = 0; c < 64; ++c){
      float4 bx = TB[lane*64 + (c ^ gsw(lane))];
      nb2 += dot4(bx, bx);
      #pragma unroll
      for (int i = 0; i < 4; ++i){
        int l = wave*4 + i;
        float4 tv = TT[l*64 + (c ^ gsw(l))];          // broadcast
        acc[i] += dot4(tv, bx);
        nt2[i] += dot4(tv, tv);
      }
    }
    float nb = fmaxf(sqrtf(nb2), 1e-12f);
    int ln = lang_num[b];
    float bacc = 0.f;
    #pragma unroll
    for (int i = 0; i < 4; ++i){
      int l = wave*4 + i;
      if (l < ln){
        float sv = acc[i] / (fmaxf(sqrtf(nt2[i]), 1e-12f) * nb);
        float wv  = w_ws [((size_t)b*L + l)*K + lane];
        float iou = iou_ws[((size_t)b*L + l)*K + lane];
        float S2 = wsum(wv);
        float target = wv / (S2 + 1e-6f);
        float tsum = S2 / (S2 + 1e-6f);
        float t2 = target / (tsum + 1e-6f);
        float z = sv * itau;
        float zmax = wmaxr(z);
        float se = wsum(expf(z - zmax));
        float lp = z - zmax - logf(se);
        float ce = -wsum(t2 * lp);
        bool neg = iou < 0.05f;
        float sneg = wmaxr(neg ? sv : -INFINITY);
        int anyneg = __any(neg);
        float spos = wsum(sv * target);
        float rank = anyneg ? fmaxf(0.2f - spos + sneg, 0.f) : 0.f;
        bacc += ce + 0.5f*rank;
      }
    }
    if (lane == 0) part[blockIdx.x*4 + wave] = bacc;
  } else {
    // ---------------- iou branch ----------------
    int idx = blockIdx.x - 64;
    int b = idx >> 2, r0 = (idx & 3)*16 + wave*4;
    float4* TI = (float4*)smem;            // [64][64] boxri swizzled
    const float4* srcI = (const float4*)(boxri + (size_t)b*K*H);
    #pragma unroll
    for (int j = 0; j < 16; ++j){
      int i4 = tid + 256*j;
      int row = i4 >> 6, c = i4 & 63;
      TI[row*64 + (c ^ gsw(row))] = srcI[i4];
    }
    // prefetch w rows for all 16 l (per-lane column m = lane); c masks l >= ln
    float wl[16];
    #pragma unroll
    for (int l = 0; l < 16; ++l) wl[l] = w_ws[((size_t)b*L + l)*K + lane];
    __syncthreads();

    float acc[4] = {0,0,0,0};
    float nm2 = 0.f;
    for (int c = 0; c < 64; ++c){
      float4 bx = TI[lane*64 + (c ^ gsw(lane))];
      nm2 += dot4(bx, bx);
      #pragma unroll
      for (int i = 0; i < 4; ++i){
        float4 kq = TI[(r0+i)*64 + (c ^ gsw(r0+i))];  // broadcast
        acc[i] += dot4(kq, bx);
      }
    }
    float nm = fmaxf(sqrtf(nm2), 1e-12f);
    float contrib = 0.f;
    #pragma unroll
    for (int i = 0; i < 4; ++i){
      float nk = __shfl(nm, r0 + i, 64);
      float sv = acc[i] / (nk * nm);
      float z = sv * itau;
      float zmax = wmaxr(z);
      float se = wsum(expf(z - zmax));
      float lp = z - zmax - logf(se);       // logp[row r0+i][col m=lane]
      float M = 0.f;
      #pragma unroll
      for (int l = 0; l < 16; ++l)
        M += c_ws[((size_t)b*L + l)*K + (r0 + i)] * wl[l];  // uniform c load
      contrib += M * lp;
    }
    float bacc = -wsum(contrib) * (1.f/64.f);
    if (lane == 0) part[256 + idx*4 + wave] = bacc;
  }
}

// ---------------- kernel 4: deterministic final reduce ----------------
__global__ __launch_bounds__(256) void k_final(const float* __restrict__ part,
                                               float* __restrict__ out)
{
  __shared__ float redI[4], redL[4];
  int tid = threadIdx.x, lane = tid & 63, wave = tid >> 6;
  float vl = part[tid];                                       // 256 lang partials
  float vi = part[256+tid] + part[512+tid] + part[768+tid] + part[1024+tid];
  vi = wsum(vi);
  vl = wsum(vl);
  if (lane == 0){ redI[wave] = vi; redL[wave] = vl; }
  __syncthreads();
  if (tid == 0){
    out[0] = (redL[0]+redL[1]+redL[2]+redL[3]) * (1.f/64.f);
    out[1] = (redI[0]+redI[1]+redI[2]+redI[3]) * (1.f/64.f);
  }
}

extern "C" void kernel_launch(void* const* d_in, const int* in_sizes, int n_in,
                              void* d_out, int out_size, void* d_ws, size_t ws_size,
                              hipStream_t stream)
{
  const float* pred_center = (const float*)d_in[0];
  const float* pred_size   = (const float*)d_in[1];
  const float* bbox_feature= (const float*)d_in[2];
  const float* obj         = (const float*)d_in[3];
  const float* lang_emb    = (const float*)d_in[4];
  const int*   lang_num    = (const int*)d_in[5];
  const float* ref_center  = (const float*)d_in[6];
  const int*   ref_cls     = (const int*)d_in[7];
  const float* ref_res     = (const float*)d_in[8];
  const float* mean_sz     = (const float*)d_in[9];
  const float* Wtext       = (const float*)d_in[10];
  const float* Wpc         = (const float*)d_in[11];
  const float* Wpci        = (const float*)d_in[12];
  const float* lit         = (const float*)d_in[13];
  const int*   epoch       = (const int*)d_in[14];

  float* ws = (float*)d_ws;
  int*   inds   = (int*)ws;                 // B*K ints
  float* iou_ws = ws + 4096;                // B*L*K
  float* w_ws   = iou_ws + B*L*K;           // B*L*K
  float* c_ws   = w_ws + B*L*K;             // B*L*K
  float* texr   = c_ws + B*L*K;             // B*L*H
  float* boxr   = texr + (size_t)B*L*H;     // B*K*H
  float* boxri  = boxr + (size_t)B*K*H;     // B*K*H
  float* part   = boxri + (size_t)B*K*H;    // 256 lang + 1024 iou wave-partials

  k_topk_iou<<<B, 256, 0, stream>>>(pred_center, pred_size, obj, ref_center,
                                    ref_cls, ref_res, mean_sz, epoch, lang_num,
                                    inds, iou_ws, w_ws, c_ws);
  k_gemm<<<dim3(144, 4), 256, 0, stream>>>(bbox_feature, inds, lang_emb,
                                           Wpc, Wpci, Wtext, boxr, boxri, texr);
  k_contrast<<<320, 256, 81920, stream>>>(texr, boxr, boxri,
                                          iou_ws, w_ws, c_ws, lang_num, lit,
                                          epoch, part);
  k_final<<<1, 256, 0, stream>>>(part, (float*)d_out);
}